// Round 7
// baseline (258.400 us; speedup 1.0000x reference)
//
#include <hip/hip_runtime.h>
#include <hip/hip_bf16.h>

// ---------------------------------------------------------------------------
// Transformer encoder layer (post-norm) on MI355X. f32 in/out, bf16 MFMA core.
// S=1024 B=8 D=512 H=8 HD=64 DFF=2048, N = S*B = 8192 rows.
// Round 18: attn occupancy 2x: 64-row q-blocks (grid 1024), LDS 40KB,
// launch_bounds(256,4) -> 4 blocks/CU. Denominator via ones-MFMA (A=ones
// => acc = sum_k P, layout-independent) kills 32 adds/tile + shfl reduce.
// embC now stores ln-domain (mask+bias) bf16; attn does exp(s+ev); embC
// build has no expf at all (pure add/cvt, overlaps under qkv MFMA).
// ---------------------------------------------------------------------------

#define S_LEN 1024
#define BATCH 8
#define DMODEL 512
#define NHEAD 8
#define HDIM 64
#define DFF 2048
#define NROWS (S_LEN * BATCH)   // 8192

typedef __bf16 bf16x8 __attribute__((ext_vector_type(8)));
typedef short  s16x4  __attribute__((ext_vector_type(4)));
typedef float  f32x4  __attribute__((ext_vector_type(4)));

// async global->LDS, 16 B per lane. LDS dest is wave-uniform base + lane*16.
__device__ __forceinline__ void gload16(const void* g, void* l) {
    __builtin_amdgcn_global_load_lds(
        (const __attribute__((address_space(1))) void*)g,
        (__attribute__((address_space(3))) void*)l, 16, 0, 0);
}

__device__ __forceinline__ void cast4(const float* __restrict__ src,
                                      __hip_bfloat16* __restrict__ dst, int off) {
    float4 v = *(const float4*)(src + (size_t)off * 4);
    union { s16x4 s; __hip_bfloat16 b[4]; } u;
    u.b[0] = __float2bfloat16(v.x); u.b[1] = __float2bfloat16(v.y);
    u.b[2] = __float2bfloat16(v.z); u.b[3] = __float2bfloat16(v.w);
    *(s16x4*)(dst + (size_t)off * 4) = u.s;
}

// ---------------------------------------------------------------------------
// prep: cast ONLY the qkv-gemm inputs (x -> xb, in_proj_w -> wqkvb).
// ---------------------------------------------------------------------------
__global__ __launch_bounds__(256)
void prep_cast_kernel(const float* __restrict__ x, const float* __restrict__ wq,
                      __hip_bfloat16* __restrict__ xb,
                      __hip_bfloat16* __restrict__ wqb) {
    const int NX = NROWS * DMODEL / 4;          // 1048576
    const int NQ = 3 * DMODEL * DMODEL / 4;     // 196608
    int i = blockIdx.x * 256 + threadIdx.x;
    if (i < NX)              cast4(x, xb, i);
    else if ((i -= NX) < NQ) cast4(wq, wqb, i);
}

// ---------------------------------------------------------------------------
// Fused qkv dispatch. Grid 3328:
//   [0,256):     embC build (ln-domain: mask+bias, bf16; no exp)
//   [256,1024):  128x128 NT GEMM, qkv scatter (Q,K->[sect][bh][s][d]; V->V^T)
//   [1024,3328): casts wob / w1b / w2b
// embC C-fragment order (consumed by attn):
//   idx = ((((h*16+qt)*4+w)*16 + kb)*64 + lane)*16 + j,  j = c*4+e
//   q = qt*64 + w*16 + (lane&15),  k = kb*64 + c*16 + (lane>>4)*4 + e
// ---------------------------------------------------------------------------
#define TSTR 136   // epilogue tile stride (elems): 272B rows, 16B-aligned

__global__ __launch_bounds__(256, 4)
void qkv_fused(const __hip_bfloat16* __restrict__ Ab,
               const __hip_bfloat16* __restrict__ Wb,
               const float* __restrict__ bias,
               __hip_bfloat16* __restrict__ outq,
               const float* __restrict__ wo, const float* __restrict__ w1,
               const float* __restrict__ w2,
               __hip_bfloat16* __restrict__ wob, __hip_bfloat16* __restrict__ w1b,
               __hip_bfloat16* __restrict__ w2b,
               const float* __restrict__ mask,
               const float* __restrict__ rel_emb,
               __hip_bfloat16* __restrict__ embC) {
    __shared__ __align__(16) __bf16 SH[128 * TSTR];

    if (blockIdx.x < 256) {
        // ---- embC build: ln-domain (mask + bias), no exp ----
        float* rt = (float*)SH;                        // 256 floats
        rt[threadIdx.x] = rel_emb[threadIdx.x];
        __syncthreads();
        int t2 = blockIdx.x * 256 + threadIdx.x;
        int qt = t2 >> 12, w = (t2 >> 10) & 3, kb = (t2 >> 6) & 15, lane = t2 & 63;
        int q = qt * 64 + w * 16 + (lane & 15);
        float em[16]; int bv[16];
#pragma unroll
        for (int j = 0; j < 16; ++j) {
            int c = j >> 2, e = j & 3;
            int k = kb * 64 + c * 16 + (lane >> 4) * 4 + e;
            int rel = k - q;
            int bucket = (rel > 0) ? 16 : 0;
            int rp = rel < 0 ? -rel : rel;
            int v;
            if (rp < 8)          v = rp;
            else if (rp < 12)    v = 8;
            else if (rp < 16)    v = 9;
            else if (rp < 23)    v = 10;
            else if (rp < 32)    v = 11;
            else if (rp < 46)    v = 12;
            else if (rp < 64)    v = 13;
            else if (rp < 91)    v = 14;
            else                 v = 15;
            bv[j] = (bucket + v) * NHEAD;
            em[j] = mask[(size_t)q * S_LEN + k];
        }
#pragma unroll
        for (int h = 0; h < NHEAD; ++h) {
            __hip_bfloat16 ov[16];
#pragma unroll
            for (int j = 0; j < 16; ++j)
                ov[j] = __float2bfloat16(em[j] + rt[bv[j] + h]);
            size_t idx = ((((size_t)h * 16 + qt) * 4 + w) * 16 + kb) * 64 + lane;
            *(uint4*)(embC + idx * 16)     = *(uint4*)&ov[0];
            *(uint4*)(embC + idx * 16 + 8) = *(uint4*)&ov[8];
        }
        return;
    }
    if (blockIdx.x >= 1024) {
        // ---- weight casts for later dispatches ----
        const int NO = DMODEL * DMODEL / 4;     // 65536
        const int N1 = DFF * DMODEL / 4;        // 262144
        int i = (blockIdx.x - 1024) * 256 + threadIdx.x;
        if (i < NO)              cast4(wo, wob, i);
        else if ((i -= NO) < N1) cast4(w1, w1b, i);
        else                     cast4(w2, w2b, i - N1);
        return;
    }

    // ---- qkv GEMM (768 blocks), m97 structure, scatter epilogue ----
    const int id = blockIdx.x - 256;
    const int by = id & 63, bx = id >> 6;
    const int w = threadIdx.x >> 6;
    const int lane = threadIdx.x & 63;
    const int m16 = lane & 15;
    const int quad = lane >> 4;
    const int row0 = by * 128;
    const int col0 = bx * 128;
    const int rowbase = (w >> 1) * 64;
    const int colbase = (w & 1) * 64;
    const int K = DMODEL;

    __bf16* As = SH;
    __bf16* Bs = SH + 128 * 64;

    const __bf16* Ap = (const __bf16*)Ab;
    const __bf16* Wp = (const __bf16*)Wb;

    const int a_row_in_grp = lane >> 3;
    const int kb_sw = (lane & 7) ^ (lane >> 3);

    f32x4 acc[4][4];
#pragma unroll
    for (int c = 0; c < 4; ++c)
#pragma unroll
        for (int r = 0; r < 4; ++r) acc[c][r] = f32x4{0, 0, 0, 0};

    for (int k0 = 0; k0 < K; k0 += 64) {
#pragma unroll
        for (int i = 0; i < 4; ++i) {
            int grp = w * 4 + i;
            int row = grp * 8 + a_row_in_grp;
            gload16(Ap + (size_t)(row0 + row) * K + k0 + kb_sw * 8,
                    (void*)(As + grp * 512));
            gload16(Wp + (size_t)(col0 + row) * K + k0 + kb_sw * 8,
                    (void*)(Bs + grp * 512));
        }
        __syncthreads();

#pragma unroll
        for (int kk = 0; kk < 2; ++kk) {
            bf16x8 af[4], bfr[4];
            int slot = (kk * 4 + quad) ^ (m16 & 7);
#pragma unroll
            for (int r = 0; r < 4; ++r)
                af[r] = *(const bf16x8*)(As + (rowbase + r * 16 + m16) * 64 + slot * 8);
#pragma unroll
            for (int c = 0; c < 4; ++c)
                bfr[c] = *(const bf16x8*)(Bs + (colbase + c * 16 + m16) * 64 + slot * 8);
#pragma unroll
            for (int c = 0; c < 4; ++c)
#pragma unroll
                for (int r = 0; r < 4; ++r)
                    acc[c][r] = __builtin_amdgcn_mfma_f32_16x16x32_bf16(
                        af[r], bfr[c], acc[c][r], 0, 0, 0);
        }
        __syncthreads();
    }

    // ---- pack acc -> SH tile, then coalesced scatter stores ----
    __hip_bfloat16* T = (__hip_bfloat16*)SH;
#pragma unroll
    for (int c = 0; c < 4; ++c) {
        int colL = colbase + c * 16 + m16;
        float bv = bias[col0 + colL];
#pragma unroll
        for (int r = 0; r < 4; ++r) {
            int rowL = rowbase + r * 16 + quad * 4;
#pragma unroll
            for (int e = 0; e < 4; ++e)
                T[(rowL + e) * TSTR + colL] = __float2bfloat16(acc[c][r][e] + bv);
        }
    }
    __syncthreads();

    const int u = threadIdx.x;
    if (col0 < 1024) {
        int rowL = u >> 1, half = u & 1;
        int gcol = col0 + half * 64;
        int sect = gcol >> 9, h = (gcol >> 6) & 7;
        int s = (row0 + rowL) >> 3, bb = (row0 + rowL) & 7;
        size_t base = ((size_t)(sect * 64 + bb * 8 + h) * S_LEN + s) * HDIM;
        __hip_bfloat16* op = outq + base;
#pragma unroll
        for (int j = 0; j < 8; ++j)
            *(uint4*)(op + j * 8) = *(const uint4*)&T[rowL * TSTR + half * 64 + j * 8];
    } else {
        // V section: out[bh][d][s]; per (bb, col): 16 consecutive s = 32B
#pragma unroll
        for (int t2 = 0; t2 < 4; ++t2) {
            int pairIdx = u * 4 + t2;
            int bb = pairIdx >> 7;
            int cl = pairIdx & 127;
            int gcol = col0 + cl;
            int h = (gcol >> 6) & 7, d = gcol & 63;
            unsigned short tv[16];
#pragma unroll
            for (int k = 0; k < 16; ++k)
                tv[k] = *(const unsigned short*)&T[(bb + 8 * k) * TSTR + cl];
            size_t base = (size_t)(128 + bb * 8 + h) * (S_LEN * HDIM)
                        + (size_t)d * S_LEN + by * 16;
            *(uint4*)(outq + base)     = *(uint4*)&tv[0];
            *(uint4*)(outq + base + 8) = *(uint4*)&tv[8];
        }
    }
}

// ---------------------------------------------------------------------------
// LDS-staged NT GEMM, 128x128 tile (m97 structure). 4 blocks/CU.
// MODE 0: f32 out, split-K2. MODE 1: bf16 out via LDS-bounce (+RELU).
// ---------------------------------------------------------------------------
template <int MODE, bool RELU>
__global__ __launch_bounds__(256, 4)
void gemm_tile(const __hip_bfloat16* __restrict__ Ab,
               const __hip_bfloat16* __restrict__ Wb,
               const float* __restrict__ bias,
               void* __restrict__ outv,
               int N, int M, int Kloop, int Kstride) {
    const int id = blockIdx.x;
    int by, bx, bz;
    if (MODE == 0) { bz = id >> 8; int rem = id & 255; by = rem & 63; bx = rem >> 6; }
    else           { bz = 0; by = id & 63; bx = id >> 6; }
    const int w = threadIdx.x >> 6;
    const int lane = threadIdx.x & 63;
    const int m16 = lane & 15;
    const int quad = lane >> 4;
    const int row0 = by * 128;
    const int col0 = bx * 128;
    const int kbase = bz * Kloop;
    const int rowbase = (w >> 1) * 64;
    const int colbase = (w & 1) * 64;

    __shared__ __align__(16) __bf16 SH[128 * TSTR];
    __bf16* As = SH;
    __bf16* Bs = SH + 128 * 64;

    const __bf16* Ap = (const __bf16*)Ab;
    const __bf16* Wp = (const __bf16*)Wb;

    const int a_row_in_grp = lane >> 3;
    const int kb_sw = (lane & 7) ^ (lane >> 3);

    f32x4 acc[4][4];
#pragma unroll
    for (int c = 0; c < 4; ++c)
#pragma unroll
        for (int r = 0; r < 4; ++r) acc[c][r] = f32x4{0, 0, 0, 0};

    for (int k0 = 0; k0 < Kloop; k0 += 64) {
#pragma unroll
        for (int i = 0; i < 4; ++i) {
            int grp = w * 4 + i;
            int row = grp * 8 + a_row_in_grp;
            gload16(Ap + (size_t)(row0 + row) * Kstride + kbase + k0 + kb_sw * 8,
                    (void*)(As + grp * 512));
            gload16(Wp + (size_t)(col0 + row) * Kstride + kbase + k0 + kb_sw * 8,
                    (void*)(Bs + grp * 512));
        }
        __syncthreads();

#pragma unroll
        for (int kk = 0; kk < 2; ++kk) {
            bf16x8 af[4], bfr[4];
            int slot = (kk * 4 + quad) ^ (m16 & 7);
#pragma unroll
            for (int r = 0; r < 4; ++r)
                af[r] = *(const bf16x8*)(As + (rowbase + r * 16 + m16) * 64 + slot * 8);
#pragma unroll
            for (int c = 0; c < 4; ++c)
                bfr[c] = *(const bf16x8*)(Bs + (colbase + c * 16 + m16) * 64 + slot * 8);
#pragma unroll
            for (int c = 0; c < 4; ++c)
#pragma unroll
                for (int r = 0; r < 4; ++r)
                    acc[c][r] = __builtin_amdgcn_mfma_f32_16x16x32_bf16(
                        af[r], bfr[c], acc[c][r], 0, 0, 0);
        }
        __syncthreads();
    }

    if (MODE == 0) {
#pragma unroll
        for (int c = 0; c < 4; ++c) {
            int col = col0 + colbase + c * 16 + m16;
            float bv = (bz != 0) ? 0.f : bias[col];
#pragma unroll
            for (int r = 0; r < 4; ++r)
#pragma unroll
                for (int e = 0; e < 4; ++e) {
                    int row = row0 + rowbase + r * 16 + quad * 4 + e;
                    ((float*)outv)[(size_t)bz * N * M + (size_t)row * M + col] =
                        acc[c][r][e] + bv;
                }
        }
    } else {
        __hip_bfloat16* T = (__hip_bfloat16*)SH;
#pragma unroll
        for (int c = 0; c < 4; ++c) {
            int colL = colbase + c * 16 + m16;
            float bv = bias[col0 + colL];
#pragma unroll
            for (int r = 0; r < 4; ++r) {
                int rowL = rowbase + r * 16 + quad * 4;
#pragma unroll
                for (int e = 0; e < 4; ++e) {
                    float v = acc[c][r][e] + bv;
                    if (RELU) v = fmaxf(v, 0.f);
                    T[(rowL + e) * TSTR + colL] = __float2bfloat16(v);
                }
            }
        }
        __syncthreads();
        const int u = threadIdx.x;
        int rowL = u >> 1, half = u & 1;
        __hip_bfloat16* op = (__hip_bfloat16*)outv
                           + (size_t)(row0 + rowL) * M + col0 + half * 64;
#pragma unroll
        for (int j = 0; j < 8; ++j)
            *(uint4*)(op + j * 8) = *(const uint4*)&T[rowL * TSTR + half * 64 + j * 8];
    }
}

// ---------------------------------------------------------------------------
// 128x64-tile GEMM (f32 out) with prefetch double-buffering (out_proj).
// ---------------------------------------------------------------------------
__global__ __launch_bounds__(256)
void gemm64_db(const __hip_bfloat16* __restrict__ Ab,
               const __hip_bfloat16* __restrict__ Wb,
               const float* __restrict__ bias,
               float* __restrict__ outf,
               int N, int M, int K) {
    const int id = blockIdx.x;
    const int by = id & 63, bx = id >> 6;
    const int w = threadIdx.x >> 6;
    const int lane = threadIdx.x & 63;
    const int m16 = lane & 15;
    const int quad = lane >> 4;
    const int row0 = by * 128;
    const int col0 = bx * 64;
    const int rowbase = w * 32;

    __shared__ __align__(16) __bf16 As[2][128 * 64];   // 32 KB
    __shared__ __align__(16) __bf16 Bs[2][64 * 64];    // 16 KB

    const __bf16* Ap = (const __bf16*)Ab;
    const __bf16* Wp = (const __bf16*)Wb;

    const int a_row_in_grp = lane >> 3;
    const int kb_sw = (lane & 7) ^ (lane >> 3);

    auto stage = [&](int k0, int p) {
#pragma unroll
        for (int i = 0; i < 4; ++i) {
            int grp = w * 4 + i;
            int row = grp * 8 + a_row_in_grp;
            gload16(Ap + (size_t)(row0 + row) * K + k0 + kb_sw * 8,
                    (void*)(&As[p][grp * 512]));
        }
#pragma unroll
        for (int i = 0; i < 2; ++i) {
            int grp = w * 2 + i;
            int row = grp * 8 + a_row_in_grp;
            gload16(Wp + (size_t)(col0 + row) * K + k0 + kb_sw * 8,
                    (void*)(&Bs[p][grp * 512]));
        }
    };

    f32x4 acc[4][2];
#pragma unroll
    for (int c = 0; c < 4; ++c)
#pragma unroll
        for (int r = 0; r < 2; ++r) acc[c][r] = f32x4{0, 0, 0, 0};

    stage(0, 0);
    __syncthreads();

    int p = 0;
    for (int k0 = 0; k0 < K; k0 += 64, p ^= 1) {
        if (k0 + 64 < K) stage(k0 + 64, p ^ 1);
#pragma unroll
        for (int kk = 0; kk < 2; ++kk) {
            bf16x8 af[2], bfr[4];
            int slot = (kk * 4 + quad) ^ (m16 & 7);
#pragma unroll
            for (int r = 0; r < 2; ++r)
                af[r] = *(const bf16x8*)(&As[p][(rowbase + r * 16 + m16) * 64 + slot * 8]);
#pragma unroll
            for (int c = 0; c < 4; ++c)
                bfr[c] = *(const bf16x8*)(&Bs[p][(c * 16 + m16) * 64 + slot * 8]);
#pragma unroll
            for (int c = 0; c < 4; ++c)
#pragma unroll
                for (int r = 0; r < 2; ++r)
                    acc[c][r] = __builtin_amdgcn_mfma_f32_16x16x32_bf16(
                        af[r], bfr[c], acc[c][r], 0, 0, 0);
        }
        __syncthreads();
    }

#pragma unroll
    for (int c = 0; c < 4; ++c) {
        int col = col0 + c * 16 + m16;
        float bv = bias[col];
#pragma unroll
        for (int r = 0; r < 2; ++r)
#pragma unroll
            for (int e = 0; e < 4; ++e) {
                int row = row0 + rowbase + r * 16 + quad * 4 + e;
                outf[(size_t)row * M + col] = acc[c][r][e] + bv;
            }
    }
}

// ---------------------------------------------------------------------------
// Flash attention v7: 64-row q-blocks, grid 1024 (h=id&7, qb=(id>>3)&15,
// b=id>>7; all users of head h on XCD h). 4 waves; wave w owns q rows
// q0 + w*16 + m16. LDS 40KB -> 4 blocks/CU. Denominator = ones-MFMA
// (A=all-ones => acc entries = sum_k P[q=m16][k]). embC is ln-domain:
// P = exp(S + ev). Epilogue transposes through dead Ks LDS.
// ---------------------------------------------------------------------------
__global__ __launch_bounds__(256, 4)
void attn_mfma(const __hip_bfloat16* __restrict__ qkv_bhsd,
               const __hip_bfloat16* __restrict__ embC,
               __hip_bfloat16* __restrict__ o) {
    const int id = blockIdx.x;
    const int h = id & 7;
    const int qb = (id >> 3) & 15;
    const int b = id >> 7;
    const int bh = b * 8 + h;
    const int q0 = qb * 64;
    const int t = threadIdx.x;
    const int w = t >> 6, lane = t & 63, m16 = lane & 15, quad = lane >> 4;

    const __bf16* Qb  = (const __bf16*)qkv_bhsd + (size_t)bh * (S_LEN * HDIM);
    const __bf16* Kb  = (const __bf16*)qkv_bhsd + (size_t)(64 + bh) * (S_LEN * HDIM);
    const __bf16* VTg = (const __bf16*)qkv_bhsd + (size_t)(128 + bh) * (S_LEN * HDIM);
    const __hip_bfloat16* ec =
        embC + ((((size_t)h * 16 + qb) * 4 + w) * 16) * 1024 + (size_t)lane * 16;

    __shared__ __align__(16) __bf16 Ks[2][64 * 64];   // 16 KB
    __shared__ __align__(16) __bf16 Vs[2][64 * 64];   // 16 KB
    __shared__ __align__(16) __bf16 P[4][16 * 64];    // 8 KB, wave-private

    const int r_in = lane >> 3;
    const int kb_sw = (lane & 7) ^ r_in;

    auto stage = [&](int kc, int p) {
#pragma unroll
        for (int i = 0; i < 2; ++i) {
            int grp = w * 2 + i;
            gload16(Kb + (size_t)(kc + grp * 8 + r_in) * HDIM + kb_sw * 8,
                    (void*)(&Ks[p][grp * 512]));
            gload16(VTg + (size_t)(grp * 8 + r_in) * S_LEN + kc + kb_sw * 8,
                    (void*)(&Vs[p][grp * 512]));
        }
    };

    // Q fragments, scaled by exact 1/8
    bf16x8 aQ0, aQ1;
    {
        const __bf16* qp = Qb + (size_t)(q0 + w * 16 + m16) * HDIM + quad * 8;
        bf16x8 t0 = *(const bf16x8*)qp;
        bf16x8 t1 = *(const bf16x8*)(qp + 32);
#pragma unroll
        for (int j = 0; j < 8; ++j) {
            t0[j] = (__bf16)((float)t0[j] * 0.125f);
            t1[j] = (__bf16)((float)t1[j] * 0.125f);
        }
        aQ0 = t0; aQ1 = t1;
    }

    // all-ones A-fragment for the denominator MFMA
    union { bf16x8 v; unsigned short us[8]; } vone;
#pragma unroll
    for (int j = 0; j < 8; ++j) vone.us[j] = 0x3F80;   // 1.0 bf16

    f32x4 accOT[4] = {f32x4{0,0,0,0}, f32x4{0,0,0,0}, f32x4{0,0,0,0}, f32x4{0,0,0,0}};
    f32x4 accL = f32x4{0, 0, 0, 0};

    stage(0, 0);
    __syncthreads();

    int p = 0;
    for (int kc = 0; kc < S_LEN; kc += 64, p ^= 1) {
        if (kc + 64 < S_LEN) stage(kc + 64, p ^ 1);

        union { uint4 u[2]; __hip_bfloat16 e[16]; } ev;
        ev.u[0] = *(const uint4*)(ec + (size_t)(kc >> 6) * 1024);
        ev.u[1] = *(const uint4*)(ec + (size_t)(kc >> 6) * 1024 + 8);

        // ---- S^T = K * Q^T ----
        f32x4 accT[4] = {f32x4{0,0,0,0}, f32x4{0,0,0,0}, f32x4{0,0,0,0}, f32x4{0,0,0,0}};
        const int sub = (m16 >> 3) * 512 + (m16 & 7) * 64;
        const int s0 = (quad ^ (m16 & 7)) * 8;
        const int s1 = ((4 + quad) ^ (m16 & 7)) * 8;
#pragma unroll
        for (int c = 0; c < 4; ++c) {
            const __bf16* kr = &Ks[p][c * 1024 + sub];
            bf16x8 b0 = *(const bf16x8*)(kr + s0);
            bf16x8 b1 = *(const bf16x8*)(kr + s1);
            accT[c] = __builtin_amdgcn_mfma_f32_16x16x32_bf16(b0, aQ0, accT[c], 0, 0, 0);
            accT[c] = __builtin_amdgcn_mfma_f32_16x16x32_bf16(b1, aQ1, accT[c], 0, 0, 0);
        }

        // ---- P^T = exp(S^T + ev) -> wave-private LDS ----
#pragma unroll
        for (int c = 0; c < 4; ++c) {
            union { s16x4 s; __hip_bfloat16 bb[4]; } u4;
#pragma unroll
            for (int e = 0; e < 4; ++e) {
                float evf = __bfloat162float(ev.e[c * 4 + e]);
                float pv = __expf(accT[c][e] + evf);
                u4.bb[e] = __float2bfloat16(pv);
            }
            int blk = (c * 2 + (quad >> 1)) ^ (m16 & 7);
            *(s16x4*)&P[w][m16 * 64 + blk * 8 + (quad & 1) * 4] = u4.s;
        }

        // ---- P^T B-fragments ----
        bf16x8 pb0 = *(const bf16x8*)&P[w][m16 * 64 + ((quad) ^ (m16 & 7)) * 8];
        bf16x8 pb1 = *(const bf16x8*)&P[w][m16 * 64 + ((4 + quad) ^ (m16 & 7)) * 8];

        // ---- O^T += V^T * P^T; denominator via ones-MFMA ----
#pragma unroll
        for (int dt = 0; dt < 4; ++dt) {
            const __bf16* vr = &Vs[p][dt * 1024 + sub];
            bf16x8 v0 = *(const bf16x8*)(vr + s0);
            bf16x8 v1 = *(const bf16x8*)(vr + s1);
            accOT[dt] = __builtin_amdgcn_mfma_f32_16x16x32_bf16(v0, pb0, accOT[dt], 0, 0, 0);
            accOT[dt] = __builtin_amdgcn_mfma_f32_16x16x32_bf16(v1, pb1, accOT[dt], 0, 0, 0);
        }
        accL = __builtin_amdgcn_mfma_f32_16x16x32_bf16(vone.v, pb0, accL, 0, 0, 0);
        accL = __builtin_amdgcn_mfma_f32_16x16x32_bf16(vone.v, pb1, accL, 0, 0, 0);

        __syncthreads();   // retire prefetch, protect Ks/Vs buffers
    }

    const float inv = 1.f / accL[0];   // all 4 entries = sum_k P[q=m16][k]

    // ---- epilogue via LDS transpose (Ks dead): lane holds
    // O^T[d = dt*16 + quad*4 + e][q = m16]; want o[q][d] coalesced ----
    {
        __bf16* Tw = ((__bf16*)Ks) + (size_t)w * 1152;   // 16 rows x 72 stride
#pragma unroll
        for (int dt = 0; dt < 4; ++dt) {
            union { s16x4 s; __hip_bfloat16 bb4[4]; } uu;
#pragma unroll
            for (int e = 0; e < 4; ++e)
                uu.bb4[e] = __float2bfloat16(accOT[dt][e] * inv);
            *(s16x4*)&Tw[m16 * 72 + dt * 16 + quad * 4] = uu.s;
        }
        asm volatile("s_waitcnt lgkmcnt(0)" ::: "memory");
        __builtin_amdgcn_sched_barrier(0);
        const int qr = lane >> 2, ch = lane & 3;
        int qg = q0 + w * 16 + qr;
        __hip_bfloat16* op = o + ((size_t)qg * BATCH + b) * DMODEL
                           + h * HDIM + ch * 16;
        *(uint4*)op       = *(const uint4*)&Tw[qr * 72 + ch * 16];
        *(uint4*)(op + 8) = *(const uint4*)&Tw[qr * 72 + ch * 16 + 8];
    }
}

// ---------------------------------------------------------------------------
// Fused residual + LayerNorm, float4-vectorized. 256 threads = 4 waves;
// wave i handles row 4*blockIdx.x + i. Bit-exact vs 64-thread version.
// ---------------------------------------------------------------------------
__global__ __launch_bounds__(256)
void ln_kernel(const float* __restrict__ resid,
               const float* __restrict__ gin,
               const float* __restrict__ gin2,
               const float* __restrict__ w,
               const float* __restrict__ b,
               float* __restrict__ outf,
               __hip_bfloat16* __restrict__ outb) {
    const int row = blockIdx.x * 4 + (threadIdx.x >> 6);
    const int lane = threadIdx.x & 63;
    const float* rp = resid + (size_t)row * DMODEL;
    const float* gp = gin + (size_t)row * DMODEL;

    float4 v[2];
    float s = 0.f, s2 = 0.f;
#pragma unroll
    for (int i = 0; i < 2; ++i) {
        int d = i * 256 + lane * 4;
        float4 a = *(const float4*)(rp + d);
        float4 g = *(const float4*)(gp + d);
        a.x += g.x; a.y += g.y; a.z += g.z; a.w += g.w;
        if (gin2) {
            float4 g2 = *(const float4*)(gin2 + (size_t)row * DMODEL + d);
            a.x += g2.x; a.y += g2.y; a.z += g2.z; a.w += g2.w;
        }
        v[i] = a;
        s += a.x + a.y + a.z + a.w;
        s2 += a.x * a.x + a.y * a.y + a.z * a.z + a.w * a.w;
    }
#pragma unroll
    for (int off = 32; off; off >>= 1) {
        s  += __shfl_xor(s, off);
        s2 += __shfl_xor(s2, off);
    }
    float mu = s * (1.f / DMODEL);
    float var = s2 * (1.f / DMODEL) - mu * mu;
    float rs = rsqrtf(var + 1e-5f);
#pragma unroll
    for (int i = 0; i < 2; ++i) {
        int d = i * 256 + lane * 4;
        float4 wv = *(const float4*)(w + d);
        float4 bv = *(const float4*)(b + d);
        float4 y;
        y.x = (v[i].x - mu) * rs * wv.x + bv.x;
        y.y = (v[i].y - mu) * rs * wv.y + bv.y;
        y.z = (v[i].z - mu) * rs * wv.z + bv.z;
        y.w = (v[i].w - mu) * rs * wv.w + bv.w;
        *(float4*)(outf + (size_t)row * DMODEL + d) = y;
        if (outb) {
            union { s16x4 s4; __hip_bfloat16 e[4]; } u;
            u.e[0] = __float2bfloat16(y.x); u.e[1] = __float2bfloat16(y.y);
            u.e[2] = __float2bfloat16(y.z); u.e[3] = __float2bfloat16(y.w);
            *(s16x4*)(outb + (size_t)row * DMODEL + d) = u.s4;
        }
    }
}

// ---------------------------------------------------------------------------
extern "C" void kernel_launch(void* const* d_in, const int* in_sizes, int n_in,
                              void* d_out, int out_size, void* d_ws, size_t ws_size,
                              hipStream_t stream) {
    const float* x          = (const float*)d_in[0];
    const float* attn_mask  = (const float*)d_in[1];
    const float* in_proj_w  = (const float*)d_in[2];
    const float* in_proj_b  = (const float*)d_in[3];
    const float* out_proj_w = (const float*)d_in[4];
    const float* out_proj_b = (const float*)d_in[5];
    const float* lin1_w     = (const float*)d_in[6];
    const float* lin1_b     = (const float*)d_in[7];
    const float* lin2_w     = (const float*)d_in[8];
    const float* lin2_b     = (const float*)d_in[9];
    const float* ln1_w      = (const float*)d_in[10];
    const float* ln1_b      = (const float*)d_in[11];
    const float* ln2_w      = (const float*)d_in[12];
    const float* ln2_b      = (const float*)d_in[13];
    const float* rel_emb    = (const float*)d_in[14];

    char* ws = (char*)d_ws;
    size_t off = 0;
    auto alloc = [&](size_t bytes) {
        char* p = ws + off;
        off += (bytes + 255) / 256 * 256;
        return (void*)p;
    };
    __hip_bfloat16* embt  = (__hip_bfloat16*)alloc((size_t)NHEAD * S_LEN * S_LEN * 2);
    __hip_bfloat16* wqkvb = (__hip_bfloat16*)alloc((size_t)3 * DMODEL * DMODEL * 2);
    __hip_bfloat16* wob   = (__hip_bfloat16*)alloc((size_t)DMODEL * DMODEL * 2);
    __hip_bfloat16* w1b   = (__hip_bfloat16*)alloc((size_t)DFF * DMODEL * 2);
    __hip_bfloat16* w2b   = (__hip_bfloat16*)alloc((size_t)DMODEL * DFF * 2);
    __hip_bfloat16* xb    = (__hip_bfloat16*)alloc((size_t)NROWS * DMODEL * 2);
    __hip_bfloat16* qkvb  = (__hip_bfloat16*)alloc((size_t)3 * 64 * S_LEN * HDIM * 2);
    __hip_bfloat16* o     = (__hip_bfloat16*)alloc((size_t)NROWS * DMODEL * 2);
    float* tmp            = (float*)alloc((size_t)2 * NROWS * DMODEL * 4);  // 2 slabs
    float* yf             = (float*)alloc((size_t)NROWS * DMODEL * 4);
    __hip_bfloat16* yb    = (__hip_bfloat16*)alloc((size_t)NROWS * DMODEL * 2);
    __hip_bfloat16* ffb   = (__hip_bfloat16*)alloc((size_t)NROWS * DFF * 2);

    float* out = (float*)d_out;
    float* tmp2 = tmp + (size_t)NROWS * DMODEL;

    // 0. cast qkv-gemm inputs only (x -> xb, in_proj_w -> wqkvb)
    prep_cast_kernel<<<dim3(4864), 256, 0, stream>>>(x, in_proj_w, xb, wqkvb);

    // 1. fused dispatch: embC (256) FIRST, qkv gemm (768), weight casts (2304)
    qkv_fused<<<dim3(3328), 256, 0, stream>>>(
        xb, wqkvb, in_proj_b, qkvb,
        out_proj_w, lin1_w, lin2_w, wob, w1b, w2b,
        attn_mask, rel_emb, embt);

    // 2. flash attention (grid 1024: 64-row q-blocks, 4 blocks/CU) -> o bf16
    attn_mfma<<<dim3(1024), 256, 0, stream>>>(qkvb, embt, o);

    // 3. tmp = o @ out_proj_w^T + out_proj_b  f32 (dbuf, flat grid 512)
    gemm64_db<<<dim3(512), 256, 0, stream>>>(
        o, wob, out_proj_b, tmp, NROWS, DMODEL, DMODEL);

    // 4. y = LN(x + tmp)
    ln_kernel<<<dim3(NROWS / 4), 256, 0, stream>>>(
        x, tmp, nullptr, ln1_w, ln1_b, yf, yb);

    // 5. ff = relu(y @ lin1_w^T + lin1_b)  bf16 (flat grid 1024, 4 blocks/CU)
    gemm_tile<1, true><<<dim3(1024), 256, 0, stream>>>(
        yb, w1b, lin1_b, ffb, NROWS, DFF, DMODEL, DMODEL);

    // 6. tmp/tmp2 = ff @ lin2_w^T + lin2_b, split-K2 f32 (flat grid 512)
    gemm_tile<0, false><<<dim3(512), 256, 0, stream>>>(
        ffb, w2b, lin2_b, tmp, NROWS, DMODEL, DFF / 2, DFF);

    // 7. out = LN(y + tmp + tmp2)  f32
    ln_kernel<<<dim3(NROWS / 4), 256, 0, stream>>>(
        yf, tmp, tmp2, ln2_w, ln2_b, out, nullptr);
}

// Round 8
// 246.507 us; speedup vs baseline: 1.0482x; 1.0482x over previous
//
#include <hip/hip_runtime.h>
#include <hip/hip_bf16.h>

// ---------------------------------------------------------------------------
// Transformer encoder layer (post-norm) on MI355X. f32 in/out, bf16 MFMA core.
// S=1024 B=8 D=512 H=8 HD=64 DFF=2048, N = S*B = 8192 rows.
// Round 19: revert to round-6 base (250.7 us proven: embC-first fused qkv,
// 2-tile attn grid 512, LDS-bounce epilogues, LN 4-row). Attn VALU cuts only:
//  - denominators via ones-MFMA (A=ones => acc = sum_k P; kills 32 adds/tile
//    /thread + both shfl reduction chains; +4 MFMAs/tile on idle matrix pipe)
//  - exp2 folding: Q scaled by 0.125/ln2, embC stores (mask+bias)/ln2 (no
//    expf anywhere in the build), attn does p = exp2(S' + ev') = add + v_exp.
// ---------------------------------------------------------------------------

#define S_LEN 1024
#define BATCH 8
#define DMODEL 512
#define NHEAD 8
#define HDIM 64
#define DFF 2048
#define NROWS (S_LEN * BATCH)   // 8192
#define RLN2 1.4426950408889634f

typedef __bf16 bf16x8 __attribute__((ext_vector_type(8)));
typedef short  s16x4  __attribute__((ext_vector_type(4)));
typedef float  f32x4  __attribute__((ext_vector_type(4)));

// async global->LDS, 16 B per lane. LDS dest is wave-uniform base + lane*16.
__device__ __forceinline__ void gload16(const void* g, void* l) {
    __builtin_amdgcn_global_load_lds(
        (const __attribute__((address_space(1))) void*)g,
        (__attribute__((address_space(3))) void*)l, 16, 0, 0);
}

__device__ __forceinline__ float fast_exp2(float x) {
#if __has_builtin(__builtin_amdgcn_exp2f)
    return __builtin_amdgcn_exp2f(x);
#else
    return exp2f(x);
#endif
}

__device__ __forceinline__ void cast4(const float* __restrict__ src,
                                      __hip_bfloat16* __restrict__ dst, int off) {
    float4 v = *(const float4*)(src + (size_t)off * 4);
    union { s16x4 s; __hip_bfloat16 b[4]; } u;
    u.b[0] = __float2bfloat16(v.x); u.b[1] = __float2bfloat16(v.y);
    u.b[2] = __float2bfloat16(v.z); u.b[3] = __float2bfloat16(v.w);
    *(s16x4*)(dst + (size_t)off * 4) = u.s;
}

// ---------------------------------------------------------------------------
// prep: cast ONLY the qkv-gemm inputs (x -> xb, in_proj_w -> wqkvb).
// ---------------------------------------------------------------------------
__global__ __launch_bounds__(256)
void prep_cast_kernel(const float* __restrict__ x, const float* __restrict__ wq,
                      __hip_bfloat16* __restrict__ xb,
                      __hip_bfloat16* __restrict__ wqb) {
    const int NX = NROWS * DMODEL / 4;          // 1048576
    const int NQ = 3 * DMODEL * DMODEL / 4;     // 196608
    int i = blockIdx.x * 256 + threadIdx.x;
    if (i < NX)              cast4(x, xb, i);
    else if ((i -= NX) < NQ) cast4(wq, wqb, i);
}

// ---------------------------------------------------------------------------
// Fused qkv dispatch. Grid 3328:
//   [0,256):     embC build: (mask + bias) * (1/ln2), bf16, no exp
//   [256,1024):  128x128 NT GEMM, qkv scatter (Q,K->[sect][bh][s][d]; V->V^T)
//   [1024,3328): casts wob / w1b / w2b
// embC C-fragment order (consumed by attn):
//   idx = ((((h*16+qt)*4+w)*16 + kb)*64 + lane)*16 + j,  j = c*4+e
//   q = qt*64 + w*16 + (lane&15),  k = kb*64 + c*16 + (lane>>4)*4 + e
// ---------------------------------------------------------------------------
#define TSTR 136   // epilogue tile stride (elems): 272B rows, 16B-aligned

__global__ __launch_bounds__(256, 4)
void qkv_fused(const __hip_bfloat16* __restrict__ Ab,
               const __hip_bfloat16* __restrict__ Wb,
               const float* __restrict__ bias,
               __hip_bfloat16* __restrict__ outq,
               const float* __restrict__ wo, const float* __restrict__ w1,
               const float* __restrict__ w2,
               __hip_bfloat16* __restrict__ wob, __hip_bfloat16* __restrict__ w1b,
               __hip_bfloat16* __restrict__ w2b,
               const float* __restrict__ mask,
               const float* __restrict__ rel_emb,
               __hip_bfloat16* __restrict__ embC) {
    __shared__ __align__(16) __bf16 SH[128 * TSTR];

    if (blockIdx.x < 256) {
        // ---- embC build: (mask + bias) / ln2, no exp ----
        float* rt = (float*)SH;                        // 256 floats
        rt[threadIdx.x] = rel_emb[threadIdx.x] * RLN2;
        __syncthreads();
        int t2 = blockIdx.x * 256 + threadIdx.x;
        int qt = t2 >> 12, w = (t2 >> 10) & 3, kb = (t2 >> 6) & 15, lane = t2 & 63;
        int q = qt * 64 + w * 16 + (lane & 15);
        float em[16]; int bv[16];
#pragma unroll
        for (int j = 0; j < 16; ++j) {
            int c = j >> 2, e = j & 3;
            int k = kb * 64 + c * 16 + (lane >> 4) * 4 + e;
            int rel = k - q;
            int bucket = (rel > 0) ? 16 : 0;
            int rp = rel < 0 ? -rel : rel;
            int v;
            if (rp < 8)          v = rp;
            else if (rp < 12)    v = 8;
            else if (rp < 16)    v = 9;
            else if (rp < 23)    v = 10;
            else if (rp < 32)    v = 11;
            else if (rp < 46)    v = 12;
            else if (rp < 64)    v = 13;
            else if (rp < 91)    v = 14;
            else                 v = 15;
            bv[j] = (bucket + v) * NHEAD;
            em[j] = mask[(size_t)q * S_LEN + k] * RLN2;
        }
#pragma unroll
        for (int h = 0; h < NHEAD; ++h) {
            __hip_bfloat16 ov[16];
#pragma unroll
            for (int j = 0; j < 16; ++j)
                ov[j] = __float2bfloat16(em[j] + rt[bv[j] + h]);
            size_t idx = ((((size_t)h * 16 + qt) * 4 + w) * 16 + kb) * 64 + lane;
            *(uint4*)(embC + idx * 16)     = *(uint4*)&ov[0];
            *(uint4*)(embC + idx * 16 + 8) = *(uint4*)&ov[8];
        }
        return;
    }
    if (blockIdx.x >= 1024) {
        // ---- weight casts for later dispatches ----
        const int NO = DMODEL * DMODEL / 4;     // 65536
        const int N1 = DFF * DMODEL / 4;        // 262144
        int i = (blockIdx.x - 1024) * 256 + threadIdx.x;
        if (i < NO)              cast4(wo, wob, i);
        else if ((i -= NO) < N1) cast4(w1, w1b, i);
        else                     cast4(w2, w2b, i - N1);
        return;
    }

    // ---- qkv GEMM (768 blocks), m97 structure, scatter epilogue ----
    const int id = blockIdx.x - 256;
    const int by = id & 63, bx = id >> 6;
    const int w = threadIdx.x >> 6;
    const int lane = threadIdx.x & 63;
    const int m16 = lane & 15;
    const int quad = lane >> 4;
    const int row0 = by * 128;
    const int col0 = bx * 128;
    const int rowbase = (w >> 1) * 64;
    const int colbase = (w & 1) * 64;
    const int K = DMODEL;

    __bf16* As = SH;
    __bf16* Bs = SH + 128 * 64;

    const __bf16* Ap = (const __bf16*)Ab;
    const __bf16* Wp = (const __bf16*)Wb;

    const int a_row_in_grp = lane >> 3;
    const int kb_sw = (lane & 7) ^ (lane >> 3);

    f32x4 acc[4][4];
#pragma unroll
    for (int c = 0; c < 4; ++c)
#pragma unroll
        for (int r = 0; r < 4; ++r) acc[c][r] = f32x4{0, 0, 0, 0};

    for (int k0 = 0; k0 < K; k0 += 64) {
#pragma unroll
        for (int i = 0; i < 4; ++i) {
            int grp = w * 4 + i;
            int row = grp * 8 + a_row_in_grp;
            gload16(Ap + (size_t)(row0 + row) * K + k0 + kb_sw * 8,
                    (void*)(As + grp * 512));
            gload16(Wp + (size_t)(col0 + row) * K + k0 + kb_sw * 8,
                    (void*)(Bs + grp * 512));
        }
        __syncthreads();

#pragma unroll
        for (int kk = 0; kk < 2; ++kk) {
            bf16x8 af[4], bfr[4];
            int slot = (kk * 4 + quad) ^ (m16 & 7);
#pragma unroll
            for (int r = 0; r < 4; ++r)
                af[r] = *(const bf16x8*)(As + (rowbase + r * 16 + m16) * 64 + slot * 8);
#pragma unroll
            for (int c = 0; c < 4; ++c)
                bfr[c] = *(const bf16x8*)(Bs + (colbase + c * 16 + m16) * 64 + slot * 8);
#pragma unroll
            for (int c = 0; c < 4; ++c)
#pragma unroll
                for (int r = 0; r < 4; ++r)
                    acc[c][r] = __builtin_amdgcn_mfma_f32_16x16x32_bf16(
                        af[r], bfr[c], acc[c][r], 0, 0, 0);
        }
        __syncthreads();
    }

    // ---- pack acc -> SH tile, then coalesced scatter stores ----
    __hip_bfloat16* T = (__hip_bfloat16*)SH;
#pragma unroll
    for (int c = 0; c < 4; ++c) {
        int colL = colbase + c * 16 + m16;
        float bv = bias[col0 + colL];
#pragma unroll
        for (int r = 0; r < 4; ++r) {
            int rowL = rowbase + r * 16 + quad * 4;
#pragma unroll
            for (int e = 0; e < 4; ++e)
                T[(rowL + e) * TSTR + colL] = __float2bfloat16(acc[c][r][e] + bv);
        }
    }
    __syncthreads();

    const int u = threadIdx.x;
    if (col0 < 1024) {
        int rowL = u >> 1, half = u & 1;
        int gcol = col0 + half * 64;
        int sect = gcol >> 9, h = (gcol >> 6) & 7;
        int s = (row0 + rowL) >> 3, bb = (row0 + rowL) & 7;
        size_t base = ((size_t)(sect * 64 + bb * 8 + h) * S_LEN + s) * HDIM;
        __hip_bfloat16* op = outq + base;
#pragma unroll
        for (int j = 0; j < 8; ++j)
            *(uint4*)(op + j * 8) = *(const uint4*)&T[rowL * TSTR + half * 64 + j * 8];
    } else {
        // V section: out[bh][d][s]; per (bb, col): 16 consecutive s = 32B
#pragma unroll
        for (int t2 = 0; t2 < 4; ++t2) {
            int pairIdx = u * 4 + t2;
            int bb = pairIdx >> 7;
            int cl = pairIdx & 127;
            int gcol = col0 + cl;
            int h = (gcol >> 6) & 7, d = gcol & 63;
            unsigned short tv[16];
#pragma unroll
            for (int k = 0; k < 16; ++k)
                tv[k] = *(const unsigned short*)&T[(bb + 8 * k) * TSTR + cl];
            size_t base = (size_t)(128 + bb * 8 + h) * (S_LEN * HDIM)
                        + (size_t)d * S_LEN + by * 16;
            *(uint4*)(outq + base)     = *(uint4*)&tv[0];
            *(uint4*)(outq + base + 8) = *(uint4*)&tv[8];
        }
    }
}

// ---------------------------------------------------------------------------
// LDS-staged NT GEMM, 128x128 tile (m97 structure). 4 blocks/CU.
// MODE 0: f32 out, split-K2. MODE 1: bf16 out via LDS-bounce (+RELU).
// ---------------------------------------------------------------------------
template <int MODE, bool RELU>
__global__ __launch_bounds__(256, 4)
void gemm_tile(const __hip_bfloat16* __restrict__ Ab,
               const __hip_bfloat16* __restrict__ Wb,
               const float* __restrict__ bias,
               void* __restrict__ outv,
               int N, int M, int Kloop, int Kstride) {
    const int id = blockIdx.x;
    int by, bx, bz;
    if (MODE == 0) { bz = id >> 8; int rem = id & 255; by = rem & 63; bx = rem >> 6; }
    else           { bz = 0; by = id & 63; bx = id >> 6; }
    const int w = threadIdx.x >> 6;
    const int lane = threadIdx.x & 63;
    const int m16 = lane & 15;
    const int quad = lane >> 4;
    const int row0 = by * 128;
    const int col0 = bx * 128;
    const int kbase = bz * Kloop;
    const int rowbase = (w >> 1) * 64;
    const int colbase = (w & 1) * 64;

    __shared__ __align__(16) __bf16 SH[128 * TSTR];
    __bf16* As = SH;
    __bf16* Bs = SH + 128 * 64;

    const __bf16* Ap = (const __bf16*)Ab;
    const __bf16* Wp = (const __bf16*)Wb;

    const int a_row_in_grp = lane >> 3;
    const int kb_sw = (lane & 7) ^ (lane >> 3);

    f32x4 acc[4][4];
#pragma unroll
    for (int c = 0; c < 4; ++c)
#pragma unroll
        for (int r = 0; r < 4; ++r) acc[c][r] = f32x4{0, 0, 0, 0};

    for (int k0 = 0; k0 < Kloop; k0 += 64) {
#pragma unroll
        for (int i = 0; i < 4; ++i) {
            int grp = w * 4 + i;
            int row = grp * 8 + a_row_in_grp;
            gload16(Ap + (size_t)(row0 + row) * Kstride + kbase + k0 + kb_sw * 8,
                    (void*)(As + grp * 512));
            gload16(Wp + (size_t)(col0 + row) * Kstride + kbase + k0 + kb_sw * 8,
                    (void*)(Bs + grp * 512));
        }
        __syncthreads();

#pragma unroll
        for (int kk = 0; kk < 2; ++kk) {
            bf16x8 af[4], bfr[4];
            int slot = (kk * 4 + quad) ^ (m16 & 7);
#pragma unroll
            for (int r = 0; r < 4; ++r)
                af[r] = *(const bf16x8*)(As + (rowbase + r * 16 + m16) * 64 + slot * 8);
#pragma unroll
            for (int c = 0; c < 4; ++c)
                bfr[c] = *(const bf16x8*)(Bs + (colbase + c * 16 + m16) * 64 + slot * 8);
#pragma unroll
            for (int c = 0; c < 4; ++c)
#pragma unroll
                for (int r = 0; r < 4; ++r)
                    acc[c][r] = __builtin_amdgcn_mfma_f32_16x16x32_bf16(
                        af[r], bfr[c], acc[c][r], 0, 0, 0);
        }
        __syncthreads();
    }

    if (MODE == 0) {
#pragma unroll
        for (int c = 0; c < 4; ++c) {
            int col = col0 + colbase + c * 16 + m16;
            float bv = (bz != 0) ? 0.f : bias[col];
#pragma unroll
            for (int r = 0; r < 4; ++r)
#pragma unroll
                for (int e = 0; e < 4; ++e) {
                    int row = row0 + rowbase + r * 16 + quad * 4 + e;
                    ((float*)outv)[(size_t)bz * N * M + (size_t)row * M + col] =
                        acc[c][r][e] + bv;
                }
        }
    } else {
        __hip_bfloat16* T = (__hip_bfloat16*)SH;
#pragma unroll
        for (int c = 0; c < 4; ++c) {
            int colL = colbase + c * 16 + m16;
            float bv = bias[col0 + colL];
#pragma unroll
            for (int r = 0; r < 4; ++r) {
                int rowL = rowbase + r * 16 + quad * 4;
#pragma unroll
                for (int e = 0; e < 4; ++e) {
                    float v = acc[c][r][e] + bv;
                    if (RELU) v = fmaxf(v, 0.f);
                    T[(rowL + e) * TSTR + colL] = __float2bfloat16(v);
                }
            }
        }
        __syncthreads();
        const int u = threadIdx.x;
        int rowL = u >> 1, half = u & 1;
        __hip_bfloat16* op = (__hip_bfloat16*)outv
                           + (size_t)(row0 + rowL) * M + col0 + half * 64;
#pragma unroll
        for (int j = 0; j < 8; ++j)
            *(uint4*)(op + j * 8) = *(const uint4*)&T[rowL * TSTR + half * 64 + j * 8];
    }
}

// ---------------------------------------------------------------------------
// 128x64-tile GEMM (f32 out) with prefetch double-buffering (out_proj).
// ---------------------------------------------------------------------------
__global__ __launch_bounds__(256)
void gemm64_db(const __hip_bfloat16* __restrict__ Ab,
               const __hip_bfloat16* __restrict__ Wb,
               const float* __restrict__ bias,
               float* __restrict__ outf,
               int N, int M, int K) {
    const int id = blockIdx.x;
    const int by = id & 63, bx = id >> 6;
    const int w = threadIdx.x >> 6;
    const int lane = threadIdx.x & 63;
    const int m16 = lane & 15;
    const int quad = lane >> 4;
    const int row0 = by * 128;
    const int col0 = bx * 64;
    const int rowbase = w * 32;

    __shared__ __align__(16) __bf16 As[2][128 * 64];   // 32 KB
    __shared__ __align__(16) __bf16 Bs[2][64 * 64];    // 16 KB

    const __bf16* Ap = (const __bf16*)Ab;
    const __bf16* Wp = (const __bf16*)Wb;

    const int a_row_in_grp = lane >> 3;
    const int kb_sw = (lane & 7) ^ (lane >> 3);

    auto stage = [&](int k0, int p) {
#pragma unroll
        for (int i = 0; i < 4; ++i) {
            int grp = w * 4 + i;
            int row = grp * 8 + a_row_in_grp;
            gload16(Ap + (size_t)(row0 + row) * K + k0 + kb_sw * 8,
                    (void*)(&As[p][grp * 512]));
        }
#pragma unroll
        for (int i = 0; i < 2; ++i) {
            int grp = w * 2 + i;
            int row = grp * 8 + a_row_in_grp;
            gload16(Wp + (size_t)(col0 + row) * K + k0 + kb_sw * 8,
                    (void*)(&Bs[p][grp * 512]));
        }
    };

    f32x4 acc[4][2];
#pragma unroll
    for (int c = 0; c < 4; ++c)
#pragma unroll
        for (int r = 0; r < 2; ++r) acc[c][r] = f32x4{0, 0, 0, 0};

    stage(0, 0);
    __syncthreads();

    int p = 0;
    for (int k0 = 0; k0 < K; k0 += 64, p ^= 1) {
        if (k0 + 64 < K) stage(k0 + 64, p ^ 1);
#pragma unroll
        for (int kk = 0; kk < 2; ++kk) {
            bf16x8 af[2], bfr[4];
            int slot = (kk * 4 + quad) ^ (m16 & 7);
#pragma unroll
            for (int r = 0; r < 2; ++r)
                af[r] = *(const bf16x8*)(&As[p][(rowbase + r * 16 + m16) * 64 + slot * 8]);
#pragma unroll
            for (int c = 0; c < 4; ++c)
                bfr[c] = *(const bf16x8*)(&Bs[p][(c * 16 + m16) * 64 + slot * 8]);
#pragma unroll
            for (int c = 0; c < 4; ++c)
#pragma unroll
                for (int r = 0; r < 2; ++r)
                    acc[c][r] = __builtin_amdgcn_mfma_f32_16x16x32_bf16(
                        af[r], bfr[c], acc[c][r], 0, 0, 0);
        }
        __syncthreads();
    }

#pragma unroll
    for (int c = 0; c < 4; ++c) {
        int col = col0 + c * 16 + m16;
        float bv = bias[col];
#pragma unroll
        for (int r = 0; r < 2; ++r)
#pragma unroll
            for (int e = 0; e < 4; ++e) {
                int row = row0 + rowbase + r * 16 + quad * 4 + e;
                outf[(size_t)row * M + col] = acc[c][r][e] + bv;
            }
    }
}

// ---------------------------------------------------------------------------
// Flash attention v6 + XCD swizzle (round-6 structure) + VALU cuts.
// Flat grid 512: h = id&7, qb = (id>>3)&7, b = id>>6. Block 256 = 4 waves;
// wave w owns q rows {q0+w*16+m16, q0+64+w*16+m16}. P = exp2(S' + ev');
// denominators via ones-MFMA. Epilogue bounces O^T through dead P[w] LDS.
// ---------------------------------------------------------------------------
__global__ __launch_bounds__(256, 2)
void attn_mfma(const __hip_bfloat16* __restrict__ qkv_bhsd,
               const __hip_bfloat16* __restrict__ embC,
               __hip_bfloat16* __restrict__ o) {
    const int id = blockIdx.x;
    const int h = id & 7;
    const int qb = (id >> 3) & 7;
    const int b = id >> 6;
    const int bh = b * 8 + h;
    const int q0 = qb * 128;
    const int t = threadIdx.x;
    const int w = t >> 6, lane = t & 63, m16 = lane & 15, quad = lane >> 4;

    const __bf16* Qb  = (const __bf16*)qkv_bhsd + (size_t)bh * (S_LEN * HDIM);
    const __bf16* Kb  = (const __bf16*)qkv_bhsd + (size_t)(64 + bh) * (S_LEN * HDIM);
    const __bf16* VTg = (const __bf16*)qkv_bhsd + (size_t)(128 + bh) * (S_LEN * HDIM);
    const int qtA = qb * 2, qtB = qtA + 1;
    const __hip_bfloat16* ecA =
        embC + ((((size_t)h * 16 + qtA) * 4 + w) * 16) * 1024 + (size_t)lane * 16;
    const __hip_bfloat16* ecB =
        embC + ((((size_t)h * 16 + qtB) * 4 + w) * 16) * 1024 + (size_t)lane * 16;

    __shared__ __align__(16) __bf16 Ks[2][64 * 64];   // 16 KB
    __shared__ __align__(16) __bf16 Vs[2][64 * 64];   // 16 KB
    __shared__ __align__(16) __bf16 P[4][2][16 * 64]; // 16 KB, wave-private

    const int r_in = lane >> 3;
    const int kb_sw = (lane & 7) ^ r_in;

    auto stage = [&](int kc, int p) {
#pragma unroll
        for (int i = 0; i < 2; ++i) {
            int grp = w * 2 + i;
            gload16(Kb + (size_t)(kc + grp * 8 + r_in) * HDIM + kb_sw * 8,
                    (void*)(&Ks[p][grp * 512]));
            gload16(VTg + (size_t)(grp * 8 + r_in) * S_LEN + kc + kb_sw * 8,
                    (void*)(&Vs[p][grp * 512]));
        }
    };

    // Q fragments for both tiles, scaled by 0.125/ln2 (exp2 folding)
    bf16x8 aQ0A, aQ1A, aQ0B, aQ1B;
    {
        const float qs = 0.125f * RLN2;
        const __bf16* qpA = Qb + (size_t)(q0 + w * 16 + m16) * HDIM + quad * 8;
        const __bf16* qpB = qpA + (size_t)64 * HDIM;
        bf16x8 t0 = *(const bf16x8*)qpA;
        bf16x8 t1 = *(const bf16x8*)(qpA + 32);
        bf16x8 t2 = *(const bf16x8*)qpB;
        bf16x8 t3 = *(const bf16x8*)(qpB + 32);
#pragma unroll
        for (int j = 0; j < 8; ++j) {
            t0[j] = (__bf16)((float)t0[j] * qs);
            t1[j] = (__bf16)((float)t1[j] * qs);
            t2[j] = (__bf16)((float)t2[j] * qs);
            t3[j] = (__bf16)((float)t3[j] * qs);
        }
        aQ0A = t0; aQ1A = t1; aQ0B = t2; aQ1B = t3;
    }

    // all-ones A-fragment for the denominator MFMAs
    union { bf16x8 v; unsigned short us[8]; } vone;
#pragma unroll
    for (int j = 0; j < 8; ++j) vone.us[j] = 0x3F80;   // 1.0 bf16

    f32x4 accOTA[4] = {f32x4{0,0,0,0}, f32x4{0,0,0,0}, f32x4{0,0,0,0}, f32x4{0,0,0,0}};
    f32x4 accOTB[4] = {f32x4{0,0,0,0}, f32x4{0,0,0,0}, f32x4{0,0,0,0}, f32x4{0,0,0,0}};
    f32x4 accLA = f32x4{0,0,0,0}, accLB = f32x4{0,0,0,0};

    stage(0, 0);
    __syncthreads();

    int p = 0;
    for (int kc = 0; kc < S_LEN; kc += 64, p ^= 1) {
        if (kc + 64 < S_LEN) stage(kc + 64, p ^ 1);

        union { uint4 u[2]; __hip_bfloat16 e[16]; } evA, evB;
        evA.u[0] = *(const uint4*)(ecA + (size_t)(kc >> 6) * 1024);
        evA.u[1] = *(const uint4*)(ecA + (size_t)(kc >> 6) * 1024 + 8);
        evB.u[0] = *(const uint4*)(ecB + (size_t)(kc >> 6) * 1024);
        evB.u[1] = *(const uint4*)(ecB + (size_t)(kc >> 6) * 1024 + 8);

        // ---- S^T = K * Q^T for both tiles ----
        f32x4 accTA[4] = {f32x4{0,0,0,0}, f32x4{0,0,0,0}, f32x4{0,0,0,0}, f32x4{0,0,0,0}};
        f32x4 accTB[4] = {f32x4{0,0,0,0}, f32x4{0,0,0,0}, f32x4{0,0,0,0}, f32x4{0,0,0,0}};
        const int sub = (m16 >> 3) * 512 + (m16 & 7) * 64;
        const int s0 = (quad ^ (m16 & 7)) * 8;
        const int s1 = ((4 + quad) ^ (m16 & 7)) * 8;
#pragma unroll
        for (int c = 0; c < 4; ++c) {
            const __bf16* kr = &Ks[p][c * 1024 + sub];
            bf16x8 b0 = *(const bf16x8*)(kr + s0);
            bf16x8 b1 = *(const bf16x8*)(kr + s1);
            accTA[c] = __builtin_amdgcn_mfma_f32_16x16x32_bf16(b0, aQ0A, accTA[c], 0, 0, 0);
            accTA[c] = __builtin_amdgcn_mfma_f32_16x16x32_bf16(b1, aQ1A, accTA[c], 0, 0, 0);
            accTB[c] = __builtin_amdgcn_mfma_f32_16x16x32_bf16(b0, aQ0B, accTB[c], 0, 0, 0);
            accTB[c] = __builtin_amdgcn_mfma_f32_16x16x32_bf16(b1, aQ1B, accTB[c], 0, 0, 0);
        }

        // ---- P^T = exp2(S^T + ev) -> wave-private LDS ----
#pragma unroll
        for (int c = 0; c < 4; ++c) {
            union { s16x4 s; __hip_bfloat16 bb[4]; } uA, uB;
#pragma unroll
            for (int e = 0; e < 4; ++e) {
                float pvA = fast_exp2(accTA[c][e] + __bfloat162float(evA.e[c * 4 + e]));
                float pvB = fast_exp2(accTB[c][e] + __bfloat162float(evB.e[c * 4 + e]));
                uA.bb[e] = __float2bfloat16(pvA);
                uB.bb[e] = __float2bfloat16(pvB);
            }
            int blk = (c * 2 + (quad >> 1)) ^ (m16 & 7);
            *(s16x4*)&P[w][0][m16 * 64 + blk * 8 + (quad & 1) * 4] = uA.s;
            *(s16x4*)&P[w][1][m16 * 64 + blk * 8 + (quad & 1) * 4] = uB.s;
        }

        // ---- P^T B-fragments ----
        bf16x8 pb0A = *(const bf16x8*)&P[w][0][m16 * 64 + ((quad) ^ (m16 & 7)) * 8];
        bf16x8 pb1A = *(const bf16x8*)&P[w][0][m16 * 64 + ((4 + quad) ^ (m16 & 7)) * 8];
        bf16x8 pb0B = *(const bf16x8*)&P[w][1][m16 * 64 + ((quad) ^ (m16 & 7)) * 8];
        bf16x8 pb1B = *(const bf16x8*)&P[w][1][m16 * 64 + ((4 + quad) ^ (m16 & 7)) * 8];

        // ---- O^T += V^T * P^T; denominators via ones-MFMA ----
#pragma unroll
        for (int dt = 0; dt < 4; ++dt) {
            const __bf16* vr = &Vs[p][dt * 1024 + sub];
            bf16x8 v0 = *(const bf16x8*)(vr + s0);
            bf16x8 v1 = *(const bf16x8*)(vr + s1);
            accOTA[dt] = __builtin_amdgcn_mfma_f32_16x16x32_bf16(v0, pb0A, accOTA[dt], 0, 0, 0);
            accOTA[dt] = __builtin_amdgcn_mfma_f32_16x16x32_bf16(v1, pb1A, accOTA[dt], 0, 0, 0);
            accOTB[dt] = __builtin_amdgcn_mfma_f32_16x16x32_bf16(v0, pb0B, accOTB[dt], 0, 0, 0);
            accOTB[dt] = __builtin_amdgcn_mfma_f32_16x16x32_bf16(v1, pb1B, accOTB[dt], 0, 0, 0);
        }
        accLA = __builtin_amdgcn_mfma_f32_16x16x32_bf16(vone.v, pb0A, accLA, 0, 0, 0);
        accLA = __builtin_amdgcn_mfma_f32_16x16x32_bf16(vone.v, pb1A, accLA, 0, 0, 0);
        accLB = __builtin_amdgcn_mfma_f32_16x16x32_bf16(vone.v, pb0B, accLB, 0, 0, 0);
        accLB = __builtin_amdgcn_mfma_f32_16x16x32_bf16(vone.v, pb1B, accLB, 0, 0, 0);

        __syncthreads();   // retire prefetch, protect Ks/Vs buffers
    }

    const float invA = 1.f / accLA[0];   // all entries = sum_k P[q=m16][k]
    const float invB = 1.f / accLB[0];

    // ---- epilogue via LDS transpose (P[w] dead) ----
    {
        __bf16* Tw = &P[w][0][0];
        const int qr = lane >> 2, ch = lane & 3;
#pragma unroll
        for (int tile = 0; tile < 2; ++tile) {
            const f32x4* accp = tile ? accOTB : accOTA;
            float inv = tile ? invB : invA;
#pragma unroll
            for (int dt = 0; dt < 4; ++dt) {
                union { s16x4 s; __hip_bfloat16 bb4[4]; } uu;
#pragma unroll
                for (int e = 0; e < 4; ++e)
                    uu.bb4[e] = __float2bfloat16(accp[dt][e] * inv);
                *(s16x4*)&Tw[m16 * 72 + dt * 16 + quad * 4] = uu.s;
            }
            asm volatile("s_waitcnt lgkmcnt(0)" ::: "memory");
            __builtin_amdgcn_sched_barrier(0);
            int qg = q0 + tile * 64 + w * 16 + qr;
            __hip_bfloat16* op = o + ((size_t)qg * BATCH + b) * DMODEL
                               + h * HDIM + ch * 16;
            *(uint4*)op       = *(const uint4*)&Tw[qr * 72 + ch * 16];
            *(uint4*)(op + 8) = *(const uint4*)&Tw[qr * 72 + ch * 16 + 8];
            asm volatile("s_waitcnt lgkmcnt(0)" ::: "memory");
            __builtin_amdgcn_sched_barrier(0);
        }
    }
}

// ---------------------------------------------------------------------------
// Fused residual + LayerNorm, float4-vectorized. 256 threads = 4 waves;
// wave i handles row 4*blockIdx.x + i. Bit-exact vs 64-thread version.
// ---------------------------------------------------------------------------
__global__ __launch_bounds__(256)
void ln_kernel(const float* __restrict__ resid,
               const float* __restrict__ gin,
               const float* __restrict__ gin2,
               const float* __restrict__ w,
               const float* __restrict__ b,
               float* __restrict__ outf,
               __hip_bfloat16* __restrict__ outb) {
    const int row = blockIdx.x * 4 + (threadIdx.x >> 6);
    const int lane = threadIdx.x & 63;
    const float* rp = resid + (size_t)row * DMODEL;
    const float* gp = gin + (size_t)row * DMODEL;

    float4 v[2];
    float s = 0.f, s2 = 0.f;
#pragma unroll
    for (int i = 0; i < 2; ++i) {
        int d = i * 256 + lane * 4;
        float4 a = *(const float4*)(rp + d);
        float4 g = *(const float4*)(gp + d);
        a.x += g.x; a.y += g.y; a.z += g.z; a.w += g.w;
        if (gin2) {
            float4 g2 = *(const float4*)(gin2 + (size_t)row * DMODEL + d);
            a.x += g2.x; a.y += g2.y; a.z += g2.z; a.w += g2.w;
        }
        v[i] = a;
        s += a.x + a.y + a.z + a.w;
        s2 += a.x * a.x + a.y * a.y + a.z * a.z + a.w * a.w;
    }
#pragma unroll
    for (int off = 32; off; off >>= 1) {
        s  += __shfl_xor(s, off);
        s2 += __shfl_xor(s2, off);
    }
    float mu = s * (1.f / DMODEL);
    float var = s2 * (1.f / DMODEL) - mu * mu;
    float rs = rsqrtf(var + 1e-5f);
#pragma unroll
    for (int i = 0; i < 2; ++i) {
        int d = i * 256 + lane * 4;
        float4 wv = *(const float4*)(w + d);
        float4 bv = *(const float4*)(b + d);
        float4 y;
        y.x = (v[i].x - mu) * rs * wv.x + bv.x;
        y.y = (v[i].y - mu) * rs * wv.y + bv.y;
        y.z = (v[i].z - mu) * rs * wv.z + bv.z;
        y.w = (v[i].w - mu) * rs * wv.w + bv.w;
        *(float4*)(outf + (size_t)row * DMODEL + d) = y;
        if (outb) {
            union { s16x4 s4; __hip_bfloat16 e[4]; } u;
            u.e[0] = __float2bfloat16(y.x); u.e[1] = __float2bfloat16(y.y);
            u.e[2] = __float2bfloat16(y.z); u.e[3] = __float2bfloat16(y.w);
            *(s16x4*)(outb + (size_t)row * DMODEL + d) = u.s4;
        }
    }
}

// ---------------------------------------------------------------------------
extern "C" void kernel_launch(void* const* d_in, const int* in_sizes, int n_in,
                              void* d_out, int out_size, void* d_ws, size_t ws_size,
                              hipStream_t stream) {
    const float* x          = (const float*)d_in[0];
    const float* attn_mask  = (const float*)d_in[1];
    const float* in_proj_w  = (const float*)d_in[2];
    const float* in_proj_b  = (const float*)d_in[3];
    const float* out_proj_w = (const float*)d_in[4];
    const float* out_proj_b = (const float*)d_in[5];
    const float* lin1_w     = (const float*)d_in[6];
    const float* lin1_b     = (const float*)d_in[7];
    const float* lin2_w     = (const float*)d_in[8];
    const float* lin2_b     = (const float*)d_in[9];
    const float* ln1_w      = (const float*)d_in[10];
    const float* ln1_b      = (const float*)d_in[11];
    const float* ln2_w      = (const float*)d_in[12];
    const float* ln2_b      = (const float*)d_in[13];
    const float* rel_emb    = (const float*)d_in[14];

    char* ws = (char*)d_ws;
    size_t off = 0;
    auto alloc = [&](size_t bytes) {
        char* p = ws + off;
        off += (bytes + 255) / 256 * 256;
        return (void*)p;
    };
    __hip_bfloat16* embt  = (__hip_bfloat16*)alloc((size_t)NHEAD * S_LEN * S_LEN * 2);
    __hip_bfloat16* wqkvb = (__hip_bfloat16*)alloc((size_t)3 * DMODEL * DMODEL * 2);
    __hip_bfloat16* wob   = (__hip_bfloat16*)alloc((size_t)DMODEL * DMODEL * 2);
    __hip_bfloat16* w1b   = (__hip_bfloat16*)alloc((size_t)DFF * DMODEL * 2);
    __hip_bfloat16* w2b   = (__hip_bfloat16*)alloc((size_t)DMODEL * DFF * 2);
    __hip_bfloat16* xb    = (__hip_bfloat16*)alloc((size_t)NROWS * DMODEL * 2);
    __hip_bfloat16* qkvb  = (__hip_bfloat16*)alloc((size_t)3 * 64 * S_LEN * HDIM * 2);
    __hip_bfloat16* o     = (__hip_bfloat16*)alloc((size_t)NROWS * DMODEL * 2);
    float* tmp            = (float*)alloc((size_t)2 * NROWS * DMODEL * 4);  // 2 slabs
    float* yf             = (float*)alloc((size_t)NROWS * DMODEL * 4);
    __hip_bfloat16* yb    = (__hip_bfloat16*)alloc((size_t)NROWS * DMODEL * 2);
    __hip_bfloat16* ffb   = (__hip_bfloat16*)alloc((size_t)NROWS * DFF * 2);

    float* out = (float*)d_out;
    float* tmp2 = tmp + (size_t)NROWS * DMODEL;

    // 0. cast qkv-gemm inputs only (x -> xb, in_proj_w -> wqkvb)
    prep_cast_kernel<<<dim3(4864), 256, 0, stream>>>(x, in_proj_w, xb, wqkvb);

    // 1. fused dispatch: embC (256) FIRST, qkv gemm (768), weight casts (2304)
    qkv_fused<<<dim3(3328), 256, 0, stream>>>(
        xb, wqkvb, in_proj_b, qkvb,
        out_proj_w, lin1_w, lin2_w, wob, w1b, w2b,
        attn_mask, rel_emb, embt);

    // 2. flash attention (XCD-swizzled flat grid 512) -> o bf16
    attn_mfma<<<dim3(512), 256, 0, stream>>>(qkvb, embt, o);

    // 3. tmp = o @ out_proj_w^T + out_proj_b  f32 (dbuf, flat grid 512)
    gemm64_db<<<dim3(512), 256, 0, stream>>>(
        o, wob, out_proj_b, tmp, NROWS, DMODEL, DMODEL);

    // 4. y = LN(x + tmp)
    ln_kernel<<<dim3(NROWS / 4), 256, 0, stream>>>(
        x, tmp, nullptr, ln1_w, ln1_b, yf, yb);

    // 5. ff = relu(y @ lin1_w^T + lin1_b)  bf16 (flat grid 1024, 4 blocks/CU)
    gemm_tile<1, true><<<dim3(1024), 256, 0, stream>>>(
        yb, w1b, lin1_b, ffb, NROWS, DFF, DMODEL, DMODEL);

    // 6. tmp/tmp2 = ff @ lin2_w^T + lin2_b, split-K2 f32 (flat grid 512)
    gemm_tile<0, false><<<dim3(512), 256, 0, stream>>>(
        ffb, w2b, lin2_b, tmp, NROWS, DMODEL, DFF / 2, DFF);

    // 7. out = LN(y + tmp + tmp2)  f32
    ln_kernel<<<dim3(NROWS / 4), 256, 0, stream>>>(
        yf, tmp, tmp2, ln2_w, ln2_b, out, nullptr);
}